// Round 3
// baseline (15521.089 us; speedup 1.0000x reference)
//
#include <hip/hip_runtime.h>
#include <cstdint>
#include <cstddef>

// ---------------------------------------------------------------------------
// GaussianBiRNN on MI355X, fp32. B=32, T=512, Din=128, H=512, Hm=256, d=32.
// out = (A[B,T,32,32], b[B,T,32], Q[B,T,32,32]) fp32, concat flat (34,078,720).
// Workspace tiers (xp / vflat / intermediates staged in d_out where legal):
//   Tier B (ws >= 218.4 MB): concurrent bidirectional scan (512 barriers).
//   Tier C (ws >= 117.7 MB): sequential scans (1024 barriers).
//   Tier D (ws >=  84.2 MB): sequential scans + concat-K head GEMMs.
// ---------------------------------------------------------------------------

#define EPS_Q 1e-4f

#define ALOAD(p)     __hip_atomic_load((p), __ATOMIC_RELAXED, __HIP_MEMORY_SCOPE_AGENT)
#define ASTORE(p, v) __hip_atomic_store((p), (v), __ATOMIC_RELAXED, __HIP_MEMORY_SCOPE_AGENT)

// ---------------- init: zero h-state + barrier flags ----------------
__global__ void init_ws_kernel(float* __restrict__ hstate, unsigned* __restrict__ flags)
{
  int i = blockIdx.x * 256 + threadIdx.x;
  if (i < 2 * 32768) hstate[i] = 0.0f;
  if (i < 768) flags[i] = 0u;
}

// ---------------- tiled fp32 GEMM: C[M,N] = A[M,K] @ W[K,N] + bias ----------
// BM=128, BN=128, BK=16, 8x8 per thread. M%128==0, K%16==0, N%4==0; N edge
// guarded (N=32, 528). Thread covers cols {tx*4..+3, 64+tx*4..+3}.
template<bool RELU>
__global__ __launch_bounds__(256)
void gemm_bias_kernel(const float* __restrict__ A, const float* __restrict__ W,
                      const float* __restrict__ bias, float* __restrict__ C,
                      int M, int N, int K)
{
  constexpr int BM = 128, BN = 128, BK = 16;
  __shared__ float As[BK][BM + 4];
  __shared__ float Bs[BK][BN + 4];

  const int tid  = threadIdx.x;
  const int tx   = tid & 15;
  const int ty   = tid >> 4;
  const int row0 = blockIdx.y * BM;
  const int col0 = blockIdx.x * BN;

  float acc[8][8];
  #pragma unroll
  for (int i = 0; i < 8; ++i)
    #pragma unroll
    for (int j = 0; j < 8; ++j) acc[i][j] = 0.f;

  for (int kk = 0; kk < K; kk += BK) {
    #pragma unroll
    for (int v = 0; v < 2; ++v) {
      const int fidx = tid + v * 256;
      const int m    = fidx >> 2;
      const int kq   = fidx & 3;
      const float4 av = *reinterpret_cast<const float4*>(
          &A[(size_t)(row0 + m) * K + kk + kq * 4]);
      As[kq * 4 + 0][m] = av.x;
      As[kq * 4 + 1][m] = av.y;
      As[kq * 4 + 2][m] = av.z;
      As[kq * 4 + 3][m] = av.w;
    }
    #pragma unroll
    for (int v = 0; v < 2; ++v) {
      const int fidx = tid + v * 256;
      const int kr   = fidx >> 5;
      const int n4   = fidx & 31;
      const int col  = col0 + n4 * 4;
      float4 bv = make_float4(0.f, 0.f, 0.f, 0.f);
      if (col < N)
        bv = *reinterpret_cast<const float4*>(&W[(size_t)(kk + kr) * N + col]);
      *reinterpret_cast<float4*>(&Bs[kr][n4 * 4]) = bv;
    }
    __syncthreads();
    #pragma unroll
    for (int k = 0; k < BK; ++k) {
      const float4 a0 = *reinterpret_cast<const float4*>(&As[k][ty * 8]);
      const float4 a1 = *reinterpret_cast<const float4*>(&As[k][ty * 8 + 4]);
      const float4 b0 = *reinterpret_cast<const float4*>(&Bs[k][tx * 4]);
      const float4 b1 = *reinterpret_cast<const float4*>(&Bs[k][64 + tx * 4]);
      const float av[8] = {a0.x, a0.y, a0.z, a0.w, a1.x, a1.y, a1.z, a1.w};
      const float bv[8] = {b0.x, b0.y, b0.z, b0.w, b1.x, b1.y, b1.z, b1.w};
      #pragma unroll
      for (int i = 0; i < 8; ++i)
        #pragma unroll
        for (int j = 0; j < 8; ++j)
          acc[i][j] = fmaf(av[i], bv[j], acc[i][j]);
    }
    __syncthreads();
  }

  #pragma unroll
  for (int h = 0; h < 2; ++h) {
    const int col = col0 + h * 64 + tx * 4;
    if (col < N) {
      const float4 bb = *reinterpret_cast<const float4*>(&bias[col]);
      #pragma unroll
      for (int i = 0; i < 8; ++i) {
        float4 o;
        o.x = acc[i][h * 4 + 0] + bb.x;
        o.y = acc[i][h * 4 + 1] + bb.y;
        o.z = acc[i][h * 4 + 2] + bb.z;
        o.w = acc[i][h * 4 + 3] + bb.w;
        if (RELU) {
          o.x = fmaxf(o.x, 0.f); o.y = fmaxf(o.y, 0.f);
          o.z = fmaxf(o.z, 0.f); o.w = fmaxf(o.w, 0.f);
        }
        *reinterpret_cast<float4*>(&C[(size_t)(row0 + ty * 8 + i) * N + col]) = o;
      }
    }
  }
}

// ---- concat-K variant: A = [A0 | A1] along K, each [M,K0] row-major. ----
// K = 2*K0, BK=16 tiles never straddle K0 (K0 % 16 == 0).
template<bool RELU>
__global__ __launch_bounds__(256)
void gemm_bias2_kernel(const float* __restrict__ A0, const float* __restrict__ A1,
                       int K0, const float* __restrict__ W,
                       const float* __restrict__ bias, float* __restrict__ C,
                       int M, int N)
{
  constexpr int BM = 128, BN = 128, BK = 16;
  __shared__ float As[BK][BM + 4];
  __shared__ float Bs[BK][BN + 4];

  const int tid  = threadIdx.x;
  const int tx   = tid & 15;
  const int ty   = tid >> 4;
  const int row0 = blockIdx.y * BM;
  const int col0 = blockIdx.x * BN;
  const int K    = 2 * K0;

  float acc[8][8];
  #pragma unroll
  for (int i = 0; i < 8; ++i)
    #pragma unroll
    for (int j = 0; j < 8; ++j) acc[i][j] = 0.f;

  for (int kk = 0; kk < K; kk += BK) {
    const float* __restrict__ Ap = (kk < K0) ? A0 : A1;
    const int kkl = (kk < K0) ? kk : kk - K0;
    #pragma unroll
    for (int v = 0; v < 2; ++v) {
      const int fidx = tid + v * 256;
      const int m    = fidx >> 2;
      const int kq   = fidx & 3;
      const float4 av = *reinterpret_cast<const float4*>(
          &Ap[(size_t)(row0 + m) * K0 + kkl + kq * 4]);
      As[kq * 4 + 0][m] = av.x;
      As[kq * 4 + 1][m] = av.y;
      As[kq * 4 + 2][m] = av.z;
      As[kq * 4 + 3][m] = av.w;
    }
    #pragma unroll
    for (int v = 0; v < 2; ++v) {
      const int fidx = tid + v * 256;
      const int kr   = fidx >> 5;
      const int n4   = fidx & 31;
      const int col  = col0 + n4 * 4;
      float4 bv = make_float4(0.f, 0.f, 0.f, 0.f);
      if (col < N)
        bv = *reinterpret_cast<const float4*>(&W[(size_t)(kk + kr) * N + col]);
      *reinterpret_cast<float4*>(&Bs[kr][n4 * 4]) = bv;
    }
    __syncthreads();
    #pragma unroll
    for (int k = 0; k < BK; ++k) {
      const float4 a0 = *reinterpret_cast<const float4*>(&As[k][ty * 8]);
      const float4 a1 = *reinterpret_cast<const float4*>(&As[k][ty * 8 + 4]);
      const float4 b0 = *reinterpret_cast<const float4*>(&Bs[k][tx * 4]);
      const float4 b1 = *reinterpret_cast<const float4*>(&Bs[k][64 + tx * 4]);
      const float av[8] = {a0.x, a0.y, a0.z, a0.w, a1.x, a1.y, a1.z, a1.w};
      const float bv[8] = {b0.x, b0.y, b0.z, b0.w, b1.x, b1.y, b1.z, b1.w};
      #pragma unroll
      for (int i = 0; i < 8; ++i)
        #pragma unroll
        for (int j = 0; j < 8; ++j)
          acc[i][j] = fmaf(av[i], bv[j], acc[i][j]);
    }
    __syncthreads();
  }

  #pragma unroll
  for (int h = 0; h < 2; ++h) {
    const int col = col0 + h * 64 + tx * 4;
    if (col < N) {
      const float4 bb = *reinterpret_cast<const float4*>(&bias[col]);
      #pragma unroll
      for (int i = 0; i < 8; ++i) {
        float4 o;
        o.x = acc[i][h * 4 + 0] + bb.x;
        o.y = acc[i][h * 4 + 1] + bb.y;
        o.z = acc[i][h * 4 + 2] + bb.z;
        o.w = acc[i][h * 4 + 3] + bb.w;
        if (RELU) {
          o.x = fmaxf(o.x, 0.f); o.y = fmaxf(o.y, 0.f);
          o.z = fmaxf(o.z, 0.f); o.w = fmaxf(o.w, 0.f);
        }
        *reinterpret_cast<float4*>(&C[(size_t)(row0 + ty * 8 + i) * N + col]) = o;
      }
    }
  }
}

// ---------------- persistent bidirectional GRU scan ----------------
// 256 WGs x 256 thr; group = bid&7 (32 WGs each), hs = bid>>3 (16 h-cols each).
//   NB=8 (CONC): dir = group>>2, b0 = (group&3)*8 — both dirs in one launch.
//   NB=4 (SEQ):  dir = dirArg,   b0 = group*4     — one dir per launch.
// Thread (kc=t&31, cg=t>>5) holds w[c][j] = Wh[kc+32j][col(cg*6+c)] in VGPRs.
// LDS time-multiplexed (one buffer): hbuf[NB*512] -> part[48*NB][33];
// wtmp[512][17] overlays during the one-time weight load. Max 50.7 KB.
// One agent-scope flag barrier per step; h-state double-buffered so a single
// barrier per step is race-free.
template<int NB>
__global__ __launch_bounds__(256, 1)
void gru_scan_kernel(const float* __restrict__ xp_f, const float* __restrict__ xp_b,
                     const float* __restrict__ fWh, const float* __restrict__ bWh,
                     const float* __restrict__ fbhn, const float* __restrict__ bbhn,
                     float* __restrict__ hstate,
                     float* __restrict__ hcat_f, float* __restrict__ hcat_b, int HS,
                     unsigned* __restrict__ flagBase, int dirArg)
{
  static_assert(NB == 4 || NB == 8, "NB");
  const int bid   = blockIdx.x;
  const int group = bid & 7;
  const int hs    = bid >> 3;                      // 0..31
  const int dir   = (NB == 8) ? (group >> 2) : dirArg;
  const int b0    = (NB == 8) ? (group & 3) * 8 : group * NB;

  const float* __restrict__ xp  = dir ? xp_b : xp_f;
  const float* __restrict__ Wh  = dir ? bWh  : fWh;
  const float* __restrict__ bhn = dir ? bbhn : fbhn;
  float* __restrict__ hcat = dir ? hcat_b : hcat_f;

  const int t  = threadIdx.x;
  const int kc = t & 31;
  const int cg = t >> 5;

  // LDS: single buffer, time-multiplexed (hbuf -> part; wtmp during init).
  constexpr int PARTF = 48 * NB * 33;              // NB=8: 12672, NB=4: 6336
  constexpr int WTF   = 512 * 17;                  // 8704
  constexpr int SMF   = (PARTF > WTF) ? PARTF : WTF;
  __shared__ float smem[SMF];
  __shared__ float nlin[16 * NB];
  float* hbuf        = smem;                       // [NB*512]
  float (*part)[33]  = reinterpret_cast<float(*)[33]>(smem);
  float (*wtmp)[17]  = reinterpret_cast<float(*)[17]>(smem);

  // --- one-time coalesced weight load (LDS-mediated, gate by gate) ---
  float w[6][16];
  for (int q = 0; q < 3; ++q) {
    #pragma unroll
    for (int v = 0; v < 8; ++v) {
      const int f   = v * 256 + t;                 // 0..2047
      const int row = f >> 2, c4 = f & 3;
      const float4 val = *reinterpret_cast<const float4*>(
          &Wh[(size_t)row * 1536 + q * 512 + hs * 16 + c4 * 4]);
      wtmp[row][c4 * 4 + 0] = val.x;
      wtmp[row][c4 * 4 + 1] = val.y;
      wtmp[row][c4 * 4 + 2] = val.z;
      wtmp[row][c4 * 4 + 3] = val.w;
    }
    __syncthreads();
    #pragma unroll
    for (int c = 0; c < 6; ++c) {
      const int cl = cg * 6 + c;
      if ((cl >> 4) == q) {
        #pragma unroll
        for (int j = 0; j < 16; ++j)
          w[c][j] = wtmp[kc + 32 * j][cl & 15];    // stride 17: conflict-free
      }
    }
    __syncthreads();
  }

  // reduce roles: low 16*NB threads -> r,z + combine; next 16*NB -> n-linear.
  const bool lowR  = (t < 16 * NB);
  const bool highR = (t >= 16 * NB) && (t < 32 * NB);
  const int  rt    = lowR ? t : (t - 16 * NB);
  const int  gi    = rt & 15;
  const int  gb    = rt >> 4;
  const float bhn_v = highR ? bhn[hs * 16 + gi] : 0.f;

  unsigned target = 0;
  unsigned* flagp = flagBase + group * 32;         // 128B-strided counters

  for (int s = 0; s < 512; ++s) {
    const int ts = dir ? (511 - s) : s;
    const float* __restrict__ hread  = hstate + (size_t)(s & 1) * 32768;
    float* __restrict__       hwrite = hstate + (size_t)((s + 1) & 1) * 32768;

    // --- stage h (agent-scope loads: cross-XCD coherent) ---
    float tmp[NB * 2];
    #pragma unroll
    for (int v = 0; v < NB * 2; ++v) {
      const int idx = v * 256 + t;
      const int b = idx >> 9, k = idx & 511;
      tmp[v] = ALOAD(&hread[((size_t)(dir * 32 + b0 + b) << 9) + k]);
    }
    float xr = 0.f, xz = 0.f, xn = 0.f, hold = 0.f;
    if (lowR) {
      const float* xrow = xp + ((size_t)(b0 + gb) * 512 + ts) * 1536 + hs * 16 + gi;
      xr = xrow[0]; xz = xrow[512]; xn = xrow[1024];
    }
    #pragma unroll
    for (int v = 0; v < NB * 2; ++v) {
      const int idx = v * 256 + t;
      hbuf[idx] = tmp[v];
    }
    __syncthreads();
    if (lowR) hold = hbuf[gb * 512 + hs * 16 + gi];

    // --- partial dots: acc[c][b] = sum_j w[c][j] * h[b][kc+32j] ---
    float acc[6][NB];
    #pragma unroll
    for (int c = 0; c < 6; ++c)
      #pragma unroll
      for (int b = 0; b < NB; ++b) acc[c][b] = 0.f;
    #pragma unroll
    for (int b = 0; b < NB; ++b) {
      float hv[16];
      #pragma unroll
      for (int j = 0; j < 16; ++j) hv[j] = hbuf[b * 512 + kc + 32 * j]; // bank=kc
      #pragma unroll
      for (int c = 0; c < 6; ++c)
        #pragma unroll
        for (int j = 0; j < 16; ++j)
          acc[c][b] = fmaf(w[c][j], hv[j], acc[c][b]);
    }
    __syncthreads();              // hbuf reads complete; smem becomes 'part'
    #pragma unroll
    for (int c = 0; c < 6; ++c)
      #pragma unroll
      for (int b = 0; b < NB; ++b)
        part[(cg * 6 + c) * NB + b][kc] = acc[c][b];
    __syncthreads();

    // --- split reduction: low = r,z; high = n-linear -> nlin ---
    float r_ = 0.f, z_ = 0.f;
    if (lowR) {
      float gr = 0.f, gz = 0.f;
      const int dr = gi * NB + gb;
      const int dz = (16 + gi) * NB + gb;
      #pragma unroll
      for (int k = 0; k < 32; ++k) gr += part[dr][k];
      #pragma unroll
      for (int k = 0; k < 32; ++k) gz += part[dz][k];
      r_ = 1.f / (1.f + expf(-(xr + gr)));
      z_ = 1.f / (1.f + expf(-(xz + gz)));
    } else if (highR) {
      float gn = 0.f;
      const int dn = (32 + gi) * NB + gb;
      #pragma unroll
      for (int k = 0; k < 32; ++k) gn += part[dn][k];
      nlin[rt] = gn + bhn_v;
    }
    __syncthreads();
    if (lowR) {
      const float n_   = tanhf(xn + r_ * nlin[rt]);
      const float hnew = (1.f - z_) * n_ + z_ * hold;
      ASTORE(&hwrite[((size_t)(dir * 32 + b0 + gb) << 9) + hs * 16 + gi], hnew);
      hcat[((size_t)(b0 + gb) * 512 + ts) * HS + hs * 16 + gi] = hnew;
    }

    // --- inter-WG barrier (32 WGs, monotonic counter) ---
    __threadfence();
    __syncthreads();
    target += 32;
    if (t == 0) {
      __hip_atomic_fetch_add(flagp, 1u, __ATOMIC_RELEASE, __HIP_MEMORY_SCOPE_AGENT);
      while (__hip_atomic_load(flagp, __ATOMIC_ACQUIRE, __HIP_MEMORY_SCOPE_AGENT) < target)
        __builtin_amdgcn_s_sleep(1);
    }
    __syncthreads();
  }
}

// ---------------- Q = L L^T from vflat (Dg[32] | tril[496]) ----------------
__global__ __launch_bounds__(256)
void q_kernel(const float* __restrict__ vflat, float* __restrict__ qout)
{
  __shared__ float vrow[528];
  __shared__ float Ls[32][33];
  const int bt = blockIdx.x;
  const int t  = threadIdx.x;
  const float* src = vflat + (size_t)bt * 528;

  for (int i = t; i < 528; i += 256) vrow[i] = src[i];
  for (int i = t; i < 32 * 33; i += 256) (&Ls[0][0])[i] = 0.f;
  __syncthreads();
  for (int e = t; e < 496; e += 256) {
    int r = (int)((1.f + sqrtf(1.f + 8.f * (float)e)) * 0.5f);
    while (r * (r - 1) / 2 > e) --r;
    while ((r + 1) * r / 2 <= e) ++r;
    const int c = e - r * (r - 1) / 2;
    Ls[r][c] = vrow[32 + e];
  }
  if (t < 32) Ls[t][t] = expf(vrow[t]) + EPS_Q;
  __syncthreads();

  float* dst = qout + (size_t)bt * 1024;
  #pragma unroll
  for (int p = 0; p < 4; ++p) {
    const int o = t + p * 256;
    const int i = o >> 5, j = o & 31;
    const int kmax = (i < j) ? i : j;
    float sum = 0.f;
    for (int k = 0; k <= kmax; ++k) sum += Ls[i][k] * Ls[j][k];
    dst[o] = sum;
  }
}

// ---------------- launch ----------------
extern "C" void kernel_launch(void* const* d_in, const int* in_sizes, int n_in,
                              void* d_out, int out_size, void* d_ws, size_t ws_size,
                              hipStream_t stream)
{
  const float* x    = (const float*)d_in[0];
  const float* iW1  = (const float*)d_in[1];
  const float* ib1  = (const float*)d_in[2];
  const float* iW2  = (const float*)d_in[3];
  const float* ib2  = (const float*)d_in[4];
  const float* fWi  = (const float*)d_in[5];
  const float* fbi  = (const float*)d_in[6];
  const float* fWh  = (const float*)d_in[7];
  const float* fbhn = (const float*)d_in[8];
  const float* bWi  = (const float*)d_in[9];
  const float* bbi  = (const float*)d_in[10];
  const float* bWh  = (const float*)d_in[11];
  const float* bbhn = (const float*)d_in[12];
  const float* mW1  = (const float*)d_in[13];
  const float* mb1  = (const float*)d_in[14];
  const float* mW2  = (const float*)d_in[15];
  const float* mb2  = (const float*)d_in[16];
  const float* vW1  = (const float*)d_in[17];
  const float* vb1  = (const float*)d_in[18];
  const float* vW2  = (const float*)d_in[19];
  const float* vb2  = (const float*)d_in[20];
  const float* dW1  = (const float*)d_in[21];
  const float* db1  = (const float*)d_in[22];
  const float* dW2  = (const float*)d_in[23];
  const float* db2  = (const float*)d_in[24];
  (void)in_sizes; (void)n_in; (void)out_size;

  float* Aout = (float*)d_out;                 // floats: A 16,777,216
  float* bout = Aout + 16777216;               //          b    524,288
  float* Qout = Aout + 17301504;               //          Q 16,777,216

  const int M = 16384;                         // B*T
  float* ws = (float*)d_ws;

  const size_t needB = 54592256ull * 4ull;     // 218.4 MB
  const size_t needC = 29426432ull * 4ull;     // 117.7 MB
  const size_t needD = 21037824ull * 4ull;     //  84.2 MB

  if (ws_size >= needB) {
    // ---- Tier B: concurrent bidirectional scan; xpb & vflat in d_out ----
    float* hid    = ws;
    float* u      = ws + 4194304;
    float* xpf    = ws + 12582912;
    float* hcat   = ws + 37748736;
    float* hstate = ws + 54525952;
    unsigned* flags = (unsigned*)(ws + 54591488);
    float* xpb    = Aout;                      // dead before b/Q/A writes
    float* vflat  = Aout;                      // dead before A write

    init_ws_kernel<<<dim3(256), dim3(256), 0, stream>>>(hstate, flags);
    gemm_bias_kernel<true ><<<dim3(2, 128),  dim3(256), 0, stream>>>(x,   iW1, ib1, hid, M, 256,  128);
    gemm_bias_kernel<false><<<dim3(4, 128),  dim3(256), 0, stream>>>(hid, iW2, ib2, u,   M, 512,  256);
    gemm_bias_kernel<false><<<dim3(12, 128), dim3(256), 0, stream>>>(u, fWi, fbi, xpf, M, 1536, 512);
    gemm_bias_kernel<false><<<dim3(12, 128), dim3(256), 0, stream>>>(u, bWi, bbi, xpb, M, 1536, 512);
    gru_scan_kernel<8><<<dim3(256), dim3(256), 0, stream>>>(
        xpf, xpb, fWh, bWh, fbhn, bbhn, hstate, hcat, hcat + 512, 1024, flags, 0);
    gemm_bias_kernel<true ><<<dim3(2, 128),  dim3(256), 0, stream>>>(hcat, mW1, mb1, hid,  M, 256,  1024);
    gemm_bias_kernel<false><<<dim3(1, 128),  dim3(256), 0, stream>>>(hid,  mW2, mb2, bout, M, 32,   256);
    gemm_bias_kernel<true ><<<dim3(2, 128),  dim3(256), 0, stream>>>(hcat, vW1, vb1, hid,   M, 256, 1024);
    gemm_bias_kernel<false><<<dim3(5, 128),  dim3(256), 0, stream>>>(hid,  vW2, vb2, vflat, M, 528, 256);
    q_kernel<<<dim3(16384), dim3(256), 0, stream>>>(vflat, Qout);
    gemm_bias_kernel<true ><<<dim3(2, 128),  dim3(256), 0, stream>>>(hcat, dW1, db1, hid,  M, 256,  1024);
    gemm_bias_kernel<false><<<dim3(8, 128),  dim3(256), 0, stream>>>(hid,  dW2, db2, Aout, M, 1024, 256);
  } else if (ws_size >= needC) {
    // ---- Tier C: sequential scans; xp & vflat in d_out ----
    float* hid    = ws;
    float* u      = ws + 4194304;
    float* hcat   = ws + 12582912;
    float* hstate = ws + 29360128;
    unsigned* flags = (unsigned*)(ws + 29425664);
    float* xp     = Aout;
    float* vflat  = Aout;

    init_ws_kernel<<<dim3(256), dim3(256), 0, stream>>>(hstate, flags);
    gemm_bias_kernel<true ><<<dim3(2, 128),  dim3(256), 0, stream>>>(x,   iW1, ib1, hid, M, 256,  128);
    gemm_bias_kernel<false><<<dim3(4, 128),  dim3(256), 0, stream>>>(hid, iW2, ib2, u,   M, 512,  256);
    gemm_bias_kernel<false><<<dim3(12, 128), dim3(256), 0, stream>>>(u, fWi, fbi, xp, M, 1536, 512);
    gru_scan_kernel<4><<<dim3(256), dim3(256), 0, stream>>>(
        xp, xp, fWh, bWh, fbhn, bbhn, hstate, hcat, hcat + 512, 1024, flags + 256, 0);
    gemm_bias_kernel<false><<<dim3(12, 128), dim3(256), 0, stream>>>(u, bWi, bbi, xp, M, 1536, 512);
    gru_scan_kernel<4><<<dim3(256), dim3(256), 0, stream>>>(
        xp, xp, fWh, bWh, fbhn, bbhn, hstate, hcat, hcat + 512, 1024, flags + 512, 1);
    gemm_bias_kernel<true ><<<dim3(2, 128),  dim3(256), 0, stream>>>(hcat, mW1, mb1, hid,  M, 256,  1024);
    gemm_bias_kernel<false><<<dim3(1, 128),  dim3(256), 0, stream>>>(hid,  mW2, mb2, bout, M, 32,   256);
    gemm_bias_kernel<true ><<<dim3(2, 128),  dim3(256), 0, stream>>>(hcat, vW1, vb1, hid,   M, 256, 1024);
    gemm_bias_kernel<false><<<dim3(5, 128),  dim3(256), 0, stream>>>(hid,  vW2, vb2, vflat, M, 528, 256);
    q_kernel<<<dim3(16384), dim3(256), 0, stream>>>(vflat, Qout);
    gemm_bias_kernel<true ><<<dim3(2, 128),  dim3(256), 0, stream>>>(hcat, dW1, db1, hid,  M, 256,  1024);
    gemm_bias_kernel<false><<<dim3(8, 128),  dim3(256), 0, stream>>>(hid,  dW2, db2, Aout, M, 1024, 256);
  } else if (ws_size >= needD) {
    // ---- Tier D: sequential scans; hf/hb/hida in ws; hid/u/xp/vflat in d_out.
    // Liveness: hidI@A[0..4.19M) -> u@A[25.69M..34.08M) -> xp@A[0..25.17M)
    // (hidI dead) -> scan_f -> hf(ws) -> xp_b@A[0..25.17M) -> scan_b -> hb(ws)
    // -> u dead. Heads read [hf|hb] (concat-K): hidm@A[0..4.19M) (xp dead),
    // bout; hidv@A[0..4.19M), vflat@A[4.19M..12.84M), Q; hida(ws), A last
    // (overwrites dead hidv/vflat; bout region untouched).
    float* hf     = ws;
    float* hb     = ws + 8388608;
    float* hida   = ws + 16777216;
    float* hstate = ws + 20971520;
    unsigned* flags = (unsigned*)(ws + 21037056);
    float* hidI   = Aout;
    float* u      = Aout + 25690112;
    float* xp     = Aout;
    float* hidm   = Aout;
    float* hidv   = Aout;
    float* vflat  = Aout + 4194304;

    init_ws_kernel<<<dim3(256), dim3(256), 0, stream>>>(hstate, flags);
    gemm_bias_kernel<true ><<<dim3(2, 128),  dim3(256), 0, stream>>>(x,    iW1, ib1, hidI, M, 256,  128);
    gemm_bias_kernel<false><<<dim3(4, 128),  dim3(256), 0, stream>>>(hidI, iW2, ib2, u,    M, 512,  256);
    gemm_bias_kernel<false><<<dim3(12, 128), dim3(256), 0, stream>>>(u, fWi, fbi, xp, M, 1536, 512);
    gru_scan_kernel<4><<<dim3(256), dim3(256), 0, stream>>>(
        xp, xp, fWh, bWh, fbhn, bbhn, hstate, hf, hb, 512, flags + 256, 0);
    gemm_bias_kernel<false><<<dim3(12, 128), dim3(256), 0, stream>>>(u, bWi, bbi, xp, M, 1536, 512);
    gru_scan_kernel<4><<<dim3(256), dim3(256), 0, stream>>>(
        xp, xp, fWh, bWh, fbhn, bbhn, hstate, hf, hb, 512, flags + 512, 1);
    gemm_bias2_kernel<true ><<<dim3(2, 128), dim3(256), 0, stream>>>(hf, hb, 512, mW1, mb1, hidm, M, 256);
    gemm_bias_kernel<false><<<dim3(1, 128),  dim3(256), 0, stream>>>(hidm, mW2, mb2, bout, M, 32, 256);
    gemm_bias2_kernel<true ><<<dim3(2, 128), dim3(256), 0, stream>>>(hf, hb, 512, vW1, vb1, hidv, M, 256);
    gemm_bias_kernel<false><<<dim3(5, 128),  dim3(256), 0, stream>>>(hidv, vW2, vb2, vflat, M, 528, 256);
    q_kernel<<<dim3(16384), dim3(256), 0, stream>>>(vflat, Qout);
    gemm_bias2_kernel<true ><<<dim3(2, 128), dim3(256), 0, stream>>>(hf, hb, 512, dW1, db1, hida, M, 256);
    gemm_bias_kernel<false><<<dim3(8, 128),  dim3(256), 0, stream>>>(hida, dW2, db2, Aout, M, 1024, 256);
  }
  // else: workspace too small — fail validation cleanly rather than corrupt.
}

// Round 5
// 5725.444 us; speedup vs baseline: 2.7109x; 2.7109x over previous
//
#include <hip/hip_runtime.h>
#include <cstdint>
#include <cstddef>

// ---------------------------------------------------------------------------
// GaussianBiRNN on MI355X, fp32. B=32, T=512, Din=128, H=512, Hm=256, d=32.
// out = (A[B,T,32,32], b[B,T,32], Q[B,T,32,32]) fp32, concat flat (34,078,720).
// Tier B layout (proven on HW round 3): ws >= 218.4 MB; xpb & vflat staged in
// d_out (dead before real outputs written); barrier slots in d_out past xpb
// (inside Qout region, fully overwritten by q_kernel afterwards).
// ---------------------------------------------------------------------------

#define EPS_Q 1e-4f

#define ALOAD(p)     __hip_atomic_load((p), __ATOMIC_RELAXED, __HIP_MEMORY_SCOPE_AGENT)
#define ASTORE(p, v) __hip_atomic_store((p), (v), __ATOMIC_RELAXED, __HIP_MEMORY_SCOPE_AGENT)

// ---------------- init: zero h-state + barrier slots ----------------
__global__ void init_ws_kernel(float* __restrict__ hstate, unsigned* __restrict__ flags)
{
  int i = blockIdx.x * 256 + threadIdx.x;
  if (i < 2 * 32768) hstate[i] = 0.0f;
  if (i < 4096) flags[i] = 0u;
}

// ---------------- tiled fp32 GEMM: C[M,N] = A[M,K] @ W[K,N] + bias ----------
// BM=128, BN=128, BK=16, 8x8 per thread. M%128==0, K%16==0, N%4==0; N edge
// guarded (N=32, 528). Thread covers cols {tx*4..+3, 64+tx*4..+3}.
template<bool RELU>
__global__ __launch_bounds__(256)
void gemm_bias_kernel(const float* __restrict__ A, const float* __restrict__ W,
                      const float* __restrict__ bias, float* __restrict__ C,
                      int M, int N, int K)
{
  constexpr int BM = 128, BN = 128, BK = 16;
  __shared__ float As[BK][BM + 4];
  __shared__ float Bs[BK][BN + 4];

  const int tid  = threadIdx.x;
  const int tx   = tid & 15;
  const int ty   = tid >> 4;
  const int row0 = blockIdx.y * BM;
  const int col0 = blockIdx.x * BN;

  float acc[8][8];
  #pragma unroll
  for (int i = 0; i < 8; ++i)
    #pragma unroll
    for (int j = 0; j < 8; ++j) acc[i][j] = 0.f;

  for (int kk = 0; kk < K; kk += BK) {
    #pragma unroll
    for (int v = 0; v < 2; ++v) {
      const int fidx = tid + v * 256;
      const int m    = fidx >> 2;
      const int kq   = fidx & 3;
      const float4 av = *reinterpret_cast<const float4*>(
          &A[(size_t)(row0 + m) * K + kk + kq * 4]);
      As[kq * 4 + 0][m] = av.x;
      As[kq * 4 + 1][m] = av.y;
      As[kq * 4 + 2][m] = av.z;
      As[kq * 4 + 3][m] = av.w;
    }
    #pragma unroll
    for (int v = 0; v < 2; ++v) {
      const int fidx = tid + v * 256;
      const int kr   = fidx >> 5;
      const int n4   = fidx & 31;
      const int col  = col0 + n4 * 4;
      float4 bv = make_float4(0.f, 0.f, 0.f, 0.f);
      if (col < N)
        bv = *reinterpret_cast<const float4*>(&W[(size_t)(kk + kr) * N + col]);
      *reinterpret_cast<float4*>(&Bs[kr][n4 * 4]) = bv;
    }
    __syncthreads();
    #pragma unroll
    for (int k = 0; k < BK; ++k) {
      const float4 a0 = *reinterpret_cast<const float4*>(&As[k][ty * 8]);
      const float4 a1 = *reinterpret_cast<const float4*>(&As[k][ty * 8 + 4]);
      const float4 b0 = *reinterpret_cast<const float4*>(&Bs[k][tx * 4]);
      const float4 b1 = *reinterpret_cast<const float4*>(&Bs[k][64 + tx * 4]);
      const float av[8] = {a0.x, a0.y, a0.z, a0.w, a1.x, a1.y, a1.z, a1.w};
      const float bv[8] = {b0.x, b0.y, b0.z, b0.w, b1.x, b1.y, b1.z, b1.w};
      #pragma unroll
      for (int i = 0; i < 8; ++i)
        #pragma unroll
        for (int j = 0; j < 8; ++j)
          acc[i][j] = fmaf(av[i], bv[j], acc[i][j]);
    }
    __syncthreads();
  }

  #pragma unroll
  for (int h = 0; h < 2; ++h) {
    const int col = col0 + h * 64 + tx * 4;
    if (col < N) {
      const float4 bb = *reinterpret_cast<const float4*>(&bias[col]);
      #pragma unroll
      for (int i = 0; i < 8; ++i) {
        float4 o;
        o.x = acc[i][h * 4 + 0] + bb.x;
        o.y = acc[i][h * 4 + 1] + bb.y;
        o.z = acc[i][h * 4 + 2] + bb.z;
        o.w = acc[i][h * 4 + 3] + bb.w;
        if (RELU) {
          o.x = fmaxf(o.x, 0.f); o.y = fmaxf(o.y, 0.f);
          o.z = fmaxf(o.z, 0.f); o.w = fmaxf(o.w, 0.f);
        }
        *reinterpret_cast<float4*>(&C[(size_t)(row0 + ty * 8 + i) * N + col]) = o;
      }
    }
  }
}

// ---------------- persistent bidirectional GRU scan ----------------
// 256 WGs x 256 thr; group = bid&7 (dir = group>>2, batch octet b0), 32 WGs
// per group each owning 16 h-cols (hs = bid>>3). Thread (kc=t&31, cg=t>>5)
// holds w[c][2jj+jo] = Wh[2kc+jo+64jj][col(cg*6+c)] in VGPRs (96 regs);
// hbuf reads are float2 (ds_read_b64, conflict-free).
// Sync per step (memory-model-correct, 1 wbl2 + 1 inv per WG per step):
//   vmcnt(0)+syncthreads  -> every wave's h-stores are resident in L2
//   t0: fetch_add(myslot,1) RELEASE  -> wbl2 pushes them to coherence pt,
//                                       then slot update visible agent-wide
//   t<32: relaxed RMW-poll of the 32 slots (RMWs execute at the coherence
//         point -> always fresh, never served from a stale local L2 line;
//         distinct 64B-strided slots -> no serialization)
//   t0: fetch_add(myslot,0) ACQUIRE  -> one buffer_inv so next step's
//                                       h loads cannot hit stale lines
// h-state double-buffered; max inter-WG skew is 1 step, which the ping-pong
// tolerates (a WG posts its slot only after its reads of buf[s&1] are done).
__global__ __launch_bounds__(256, 1)
void gru_scan_kernel(const float* __restrict__ xp_f, const float* __restrict__ xp_b,
                     const float* __restrict__ fWh, const float* __restrict__ bWh,
                     const float* __restrict__ fbhn, const float* __restrict__ bbhn,
                     float* __restrict__ hstate, float* __restrict__ hcat,
                     unsigned* __restrict__ flags)
{
  const int bid   = blockIdx.x;
  const int group = bid & 7;
  const int hs    = bid >> 3;          // 0..31: h-col slice AND wg-index in group
  const int dir   = group >> 2;
  const int b0    = (group & 3) * 8;

  const float* __restrict__ xp  = dir ? xp_b : xp_f;
  const float* __restrict__ Wh  = dir ? bWh  : fWh;
  const float* __restrict__ bhn = dir ? bbhn : fbhn;

  const int t  = threadIdx.x;
  const int kc = t & 31;
  const int cg = t >> 5;

  // LDS: single buffer, time-multiplexed. hbuf[8*512] -> part[384][33];
  // wtmp[512][17] overlays during one-time weight load. 51,200 B total.
  __shared__ float smem[384 * 33];
  __shared__ float nlin[128];
  float* hbuf        = smem;
  float (*part)[33]  = reinterpret_cast<float(*)[33]>(smem);
  float (*wtmp)[17]  = reinterpret_cast<float(*)[17]>(smem);

  // --- one-time coalesced weight load (LDS-mediated, gate by gate) ---
  float w[6][16];
  for (int q = 0; q < 3; ++q) {
    #pragma unroll
    for (int v = 0; v < 8; ++v) {
      const int f   = v * 256 + t;                 // 0..2047
      const int row = f >> 2, c4 = f & 3;
      const float4 val = *reinterpret_cast<const float4*>(
          &Wh[(size_t)row * 1536 + q * 512 + hs * 16 + c4 * 4]);
      wtmp[row][c4 * 4 + 0] = val.x;
      wtmp[row][c4 * 4 + 1] = val.y;
      wtmp[row][c4 * 4 + 2] = val.z;
      wtmp[row][c4 * 4 + 3] = val.w;
    }
    __syncthreads();
    #pragma unroll
    for (int c = 0; c < 6; ++c) {
      const int cl = cg * 6 + c;
      if ((cl >> 4) == q) {
        #pragma unroll
        for (int jj = 0; jj < 8; ++jj)
          #pragma unroll
          for (int jo = 0; jo < 2; ++jo)
            w[c][jj * 2 + jo] = wtmp[kc * 2 + jo + 64 * jj][cl & 15];
      }
    }
    __syncthreads();
  }

  // roles: low 128 threads -> r,z + combine + output; next 128 -> n-linear.
  const bool lowR  = (t < 128);
  const int  rt    = lowR ? t : (t - 128);
  const int  gi    = rt & 15;
  const int  gb    = rt >> 4;
  const float bhn_v = (!lowR) ? bhn[hs * 16 + gi] : 0.f;

  unsigned* myslot = flags + (group * 32 + hs) * 16;   // 64B-strided slots

  for (int s = 0; s < 512; ++s) {
    const int ts = dir ? (511 - s) : s;
    const float* __restrict__ hread  = hstate + (size_t)(s & 1) * 32768;
    float* __restrict__       hwrite = hstate + (size_t)((s + 1) & 1) * 32768;

    // --- stage h (agent-scope loads) ---
    float tmp[16];
    #pragma unroll
    for (int v = 0; v < 16; ++v) {
      const int idx = v * 256 + t;
      const int b = idx >> 9, k = idx & 511;
      tmp[v] = ALOAD(&hread[((size_t)(dir * 32 + b0 + b) << 9) + k]);
    }
    float xr = 0.f, xz = 0.f, xn = 0.f, hold = 0.f;
    if (lowR) {
      const float* xrow = xp + ((size_t)(b0 + gb) * 512 + ts) * 1536 + hs * 16 + gi;
      xr = xrow[0]; xz = xrow[512]; xn = xrow[1024];
    }
    #pragma unroll
    for (int v = 0; v < 16; ++v) hbuf[v * 256 + t] = tmp[v];
    __syncthreads();
    if (lowR) hold = hbuf[gb * 512 + hs * 16 + gi];

    // --- partial dots: acc[c][b] = sum_k w[c][k] * h[b][2kc+jo+64jj] ---
    float acc[6][8];
    #pragma unroll
    for (int c = 0; c < 6; ++c)
      #pragma unroll
      for (int b = 0; b < 8; ++b) acc[c][b] = 0.f;
    #pragma unroll
    for (int b = 0; b < 8; ++b) {
      #pragma unroll
      for (int jj = 0; jj < 8; ++jj) {
        const float2 h2 = *reinterpret_cast<const float2*>(
            &hbuf[b * 512 + kc * 2 + 64 * jj]);        // ds_read_b64, conflict-free
        #pragma unroll
        for (int c = 0; c < 6; ++c)
          acc[c][b] = fmaf(w[c][jj * 2], h2.x,
                      fmaf(w[c][jj * 2 + 1], h2.y, acc[c][b]));
      }
    }
    __syncthreads();              // hbuf reads complete; smem becomes 'part'
    #pragma unroll
    for (int c = 0; c < 6; ++c)
      #pragma unroll
      for (int b = 0; b < 8; ++b)
        part[b * 48 + cg * 6 + c][kc] = acc[c][b];     // batch-major: 2-way max
    __syncthreads();

    // --- split reduction (2-way banks: dr mod 32 distinct across lanes) ---
    float r_ = 0.f, z_ = 0.f;
    if (lowR) {
      float gr = 0.f, gz = 0.f;
      const int dr = gb * 48 + gi;
      const int dz = gb * 48 + 16 + gi;
      #pragma unroll
      for (int k = 0; k < 32; ++k) gr += part[dr][k];
      #pragma unroll
      for (int k = 0; k < 32; ++k) gz += part[dz][k];
      r_ = 1.f / (1.f + expf(-(xr + gr)));
      z_ = 1.f / (1.f + expf(-(xz + gz)));
    } else {
      float gn = 0.f;
      const int dn = gb * 48 + 32 + gi;
      #pragma unroll
      for (int k = 0; k < 32; ++k) gn += part[dn][k];
      nlin[rt] = gn + bhn_v;
    }
    __syncthreads();
    if (lowR) {
      const float n_   = tanhf(xn + r_ * nlin[rt]);
      const float hnew = (1.f - z_) * n_ + z_ * hold;
      ASTORE(&hwrite[((size_t)(dir * 32 + b0 + gb) << 9) + hs * 16 + gi], hnew);
      hcat[((size_t)(b0 + gb) * 512 + ts) * 1024 + (size_t)dir * 512 + hs * 16 + gi] = hnew;
    }

    // --- slot barrier: release once, relaxed RMW polls, acquire once ---
    const unsigned target = (unsigned)(s + 1);
    asm volatile("s_waitcnt vmcnt(0)" ::: "memory");   // wave's stores in L2
    __syncthreads();                                   // all waves done
    if (t == 0)
      __hip_atomic_fetch_add(myslot, 1u, __ATOMIC_RELEASE, __HIP_MEMORY_SCOPE_AGENT);
    if (t < 32) {
      unsigned* ps = flags + (group * 32 + t) * 16;
      while (__hip_atomic_fetch_add(ps, 0u, __ATOMIC_RELAXED, __HIP_MEMORY_SCOPE_AGENT) < target)
        __builtin_amdgcn_s_sleep(1);
    }
    __syncthreads();                                   // all polls satisfied
    if (t == 0)
      (void)__hip_atomic_fetch_add(myslot, 0u, __ATOMIC_ACQUIRE, __HIP_MEMORY_SCOPE_AGENT);
    __syncthreads();                                   // inv before next h loads
  }
}

// ---------------- Q = L L^T from vflat (Dg[32] | tril[496]) ----------------
__global__ __launch_bounds__(256)
void q_kernel(const float* __restrict__ vflat, float* __restrict__ qout)
{
  __shared__ float vrow[528];
  __shared__ float Ls[32][33];
  const int bt = blockIdx.x;
  const int t  = threadIdx.x;
  const float* src = vflat + (size_t)bt * 528;

  for (int i = t; i < 528; i += 256) vrow[i] = src[i];
  for (int i = t; i < 32 * 33; i += 256) (&Ls[0][0])[i] = 0.f;
  __syncthreads();
  for (int e = t; e < 496; e += 256) {
    int r = (int)((1.f + sqrtf(1.f + 8.f * (float)e)) * 0.5f);
    while (r * (r - 1) / 2 > e) --r;
    while ((r + 1) * r / 2 <= e) ++r;
    const int c = e - r * (r - 1) / 2;
    Ls[r][c] = vrow[32 + e];
  }
  if (t < 32) Ls[t][t] = expf(vrow[t]) + EPS_Q;
  __syncthreads();

  float* dst = qout + (size_t)bt * 1024;
  #pragma unroll
  for (int p = 0; p < 4; ++p) {
    const int o = t + p * 256;
    const int i = o >> 5, j = o & 31;
    const int kmax = (i < j) ? i : j;
    float sum = 0.f;
    for (int k = 0; k <= kmax; ++k) sum += Ls[i][k] * Ls[j][k];
    dst[o] = sum;
  }
}

// ---------------- launch ----------------
extern "C" void kernel_launch(void* const* d_in, const int* in_sizes, int n_in,
                              void* d_out, int out_size, void* d_ws, size_t ws_size,
                              hipStream_t stream)
{
  const float* x    = (const float*)d_in[0];
  const float* iW1  = (const float*)d_in[1];
  const float* ib1  = (const float*)d_in[2];
  const float* iW2  = (const float*)d_in[3];
  const float* ib2  = (const float*)d_in[4];
  const float* fWi  = (const float*)d_in[5];
  const float* fbi  = (const float*)d_in[6];
  const float* fWh  = (const float*)d_in[7];
  const float* fbhn = (const float*)d_in[8];
  const float* bWi  = (const float*)d_in[9];
  const float* bbi  = (const float*)d_in[10];
  const float* bWh  = (const float*)d_in[11];
  const float* bbhn = (const float*)d_in[12];
  const float* mW1  = (const float*)d_in[13];
  const float* mb1  = (const float*)d_in[14];
  const float* mW2  = (const float*)d_in[15];
  const float* mb2  = (const float*)d_in[16];
  const float* vW1  = (const float*)d_in[17];
  const float* vb1  = (const float*)d_in[18];
  const float* vW2  = (const float*)d_in[19];
  const float* vb2  = (const float*)d_in[20];
  const float* dW1  = (const float*)d_in[21];
  const float* db1  = (const float*)d_in[22];
  const float* dW2  = (const float*)d_in[23];
  const float* db2  = (const float*)d_in[24];
  (void)in_sizes; (void)n_in; (void)out_size;

  float* Aout = (float*)d_out;                 // floats: A 16,777,216
  float* bout = Aout + 16777216;               //          b    524,288
  float* Qout = Aout + 17301504;               //          Q 16,777,216

  const int M = 16384;                         // B*T
  float* ws = (float*)d_ws;

  const size_t needB = 54592256ull * 4ull;     // 218.4 MB (proven available r3)
  if (ws_size < needB) return;                 // clean validation failure

  float* hid    = ws;                          //  4,194,304
  float* u      = ws + 4194304;                //  8,388,608
  float* xpf    = ws + 12582912;               // 25,165,824
  float* hcat   = ws + 37748736;               // 16,777,216
  float* hstate = ws + 54525952;               //     65,536
  float* xpb    = Aout;                        // d_out[0..25.17M): dead before
  float* vflat  = Aout;                        //   b/Q/A writes
  unsigned* flags = (unsigned*)(Aout + 25165824);  // past xpb; dead after scan

  init_ws_kernel<<<dim3(256), dim3(256), 0, stream>>>(hstate, flags);
  // input MLP
  gemm_bias_kernel<true ><<<dim3(2, 128),  dim3(256), 0, stream>>>(x,   iW1, ib1, hid, M, 256,  128);
  gemm_bias_kernel<false><<<dim3(4, 128),  dim3(256), 0, stream>>>(hid, iW2, ib2, u,   M, 512,  256);
  // xp = u@Wi + bi (both directions)
  gemm_bias_kernel<false><<<dim3(12, 128), dim3(256), 0, stream>>>(u, fWi, fbi, xpf, M, 1536, 512);
  gemm_bias_kernel<false><<<dim3(12, 128), dim3(256), 0, stream>>>(u, bWi, bbi, xpb, M, 1536, 512);
  // bidirectional GRU scan
  gru_scan_kernel<<<dim3(256), dim3(256), 0, stream>>>(
      xpf, xpb, fWh, bWh, fbhn, bbhn, hstate, hcat, flags);
  // b head
  gemm_bias_kernel<true ><<<dim3(2, 128),  dim3(256), 0, stream>>>(hcat, mW1, mb1, hid,  M, 256,  1024);
  gemm_bias_kernel<false><<<dim3(1, 128),  dim3(256), 0, stream>>>(hid,  mW2, mb2, bout, M, 32,   256);
  // v head -> vflat -> Q
  gemm_bias_kernel<true ><<<dim3(2, 128),  dim3(256), 0, stream>>>(hcat, vW1, vb1, hid,   M, 256, 1024);
  gemm_bias_kernel<false><<<dim3(5, 128),  dim3(256), 0, stream>>>(hid,  vW2, vb2, vflat, M, 528, 256);
  q_kernel<<<dim3(16384), dim3(256), 0, stream>>>(vflat, Qout);
  // A head
  gemm_bias_kernel<true ><<<dim3(2, 128),  dim3(256), 0, stream>>>(hcat, dW1, db1, hid,  M, 256,  1024);
  gemm_bias_kernel<false><<<dim3(8, 128),  dim3(256), 0, stream>>>(hid,  dW2, db2, Aout, M, 1024, 256);
}

// Round 7
// 3991.632 us; speedup vs baseline: 3.8884x; 1.4344x over previous
//
#include <hip/hip_runtime.h>
#include <cstdint>
#include <cstddef>

// ---------------------------------------------------------------------------
// GaussianBiRNN on MI355X, fp32. B=32, T=512, Din=128, H=512, Hm=256, d=32.
// out = (A[B,T,32,32], b[B,T,32], Q[B,T,32,32]) fp32, concat flat (34,078,720).
// Tier B layout (proven on HW rounds 3/5): ws >= 218.4 MB; xpb & vflat staged
// in d_out (dead before real outputs written); barrier slots in d_out past xpb.
// Scan sync v3: h-state moves through the coherence point ONLY (system-scope
// write-through stores + system-scope bypass loads); slot barrier is pure
// relaxed RMWs. Zero wbl2 / buffer_inv in the 512-step loop.
// ---------------------------------------------------------------------------

#define EPS_Q 1e-4f

// h-state: system scope = sc0|sc1 bits -> write-through / read-at-coherence-pt.
#define HSTORE(p, v) __hip_atomic_store((p), (v), __ATOMIC_RELAXED, __HIP_MEMORY_SCOPE_SYSTEM)
#define HLOAD(p)     __hip_atomic_load((p), __ATOMIC_RELAXED, __HIP_MEMORY_SCOPE_SYSTEM)

// ---------------- init: zero h-state + barrier slots ----------------
__global__ void init_ws_kernel(float* __restrict__ hstate, unsigned* __restrict__ flags)
{
  int i = blockIdx.x * 256 + threadIdx.x;
  if (i < 2 * 32768) hstate[i] = 0.0f;
  if (i < 4096) flags[i] = 0u;
}

// ---------------- tiled fp32 GEMM: C[M,N] = A[M,K] @ W[K,N] + bias ----------
// BM=128, BN=128, BK=16, 8x8 per thread. M%128==0, K%16==0, N%4==0; N edge
// guarded (N=32, 528). Thread covers cols {tx*4..+3, 64+tx*4..+3}.
template<bool RELU>
__global__ __launch_bounds__(256)
void gemm_bias_kernel(const float* __restrict__ A, const float* __restrict__ W,
                      const float* __restrict__ bias, float* __restrict__ C,
                      int M, int N, int K)
{
  constexpr int BM = 128, BN = 128, BK = 16;
  __shared__ float As[BK][BM + 4];
  __shared__ float Bs[BK][BN + 4];

  const int tid  = threadIdx.x;
  const int tx   = tid & 15;
  const int ty   = tid >> 4;
  const int row0 = blockIdx.y * BM;
  const int col0 = blockIdx.x * BN;

  float acc[8][8];
  #pragma unroll
  for (int i = 0; i < 8; ++i)
    #pragma unroll
    for (int j = 0; j < 8; ++j) acc[i][j] = 0.f;

  for (int kk = 0; kk < K; kk += BK) {
    #pragma unroll
    for (int v = 0; v < 2; ++v) {
      const int fidx = tid + v * 256;
      const int m    = fidx >> 2;
      const int kq   = fidx & 3;
      const float4 av = *reinterpret_cast<const float4*>(
          &A[(size_t)(row0 + m) * K + kk + kq * 4]);
      As[kq * 4 + 0][m] = av.x;
      As[kq * 4 + 1][m] = av.y;
      As[kq * 4 + 2][m] = av.z;
      As[kq * 4 + 3][m] = av.w;
    }
    #pragma unroll
    for (int v = 0; v < 2; ++v) {
      const int fidx = tid + v * 256;
      const int kr   = fidx >> 5;
      const int n4   = fidx & 31;
      const int col  = col0 + n4 * 4;
      float4 bv = make_float4(0.f, 0.f, 0.f, 0.f);
      if (col < N)
        bv = *reinterpret_cast<const float4*>(&W[(size_t)(kk + kr) * N + col]);
      *reinterpret_cast<float4*>(&Bs[kr][n4 * 4]) = bv;
    }
    __syncthreads();
    #pragma unroll
    for (int k = 0; k < BK; ++k) {
      const float4 a0 = *reinterpret_cast<const float4*>(&As[k][ty * 8]);
      const float4 a1 = *reinterpret_cast<const float4*>(&As[k][ty * 8 + 4]);
      const float4 b0 = *reinterpret_cast<const float4*>(&Bs[k][tx * 4]);
      const float4 b1 = *reinterpret_cast<const float4*>(&Bs[k][64 + tx * 4]);
      const float av[8] = {a0.x, a0.y, a0.z, a0.w, a1.x, a1.y, a1.z, a1.w};
      const float bv[8] = {b0.x, b0.y, b0.z, b0.w, b1.x, b1.y, b1.z, b1.w};
      #pragma unroll
      for (int i = 0; i < 8; ++i)
        #pragma unroll
        for (int j = 0; j < 8; ++j)
          acc[i][j] = fmaf(av[i], bv[j], acc[i][j]);
    }
    __syncthreads();
  }

  #pragma unroll
  for (int h = 0; h < 2; ++h) {
    const int col = col0 + h * 64 + tx * 4;
    if (col < N) {
      const float4 bb = *reinterpret_cast<const float4*>(&bias[col]);
      #pragma unroll
      for (int i = 0; i < 8; ++i) {
        float4 o;
        o.x = acc[i][h * 4 + 0] + bb.x;
        o.y = acc[i][h * 4 + 1] + bb.y;
        o.z = acc[i][h * 4 + 2] + bb.z;
        o.w = acc[i][h * 4 + 3] + bb.w;
        if (RELU) {
          o.x = fmaxf(o.x, 0.f); o.y = fmaxf(o.y, 0.f);
          o.z = fmaxf(o.z, 0.f); o.w = fmaxf(o.w, 0.f);
        }
        *reinterpret_cast<float4*>(&C[(size_t)(row0 + ty * 8 + i) * N + col]) = o;
      }
    }
  }
}

// ---------------- persistent bidirectional GRU scan ----------------
// 256 WGs x 256 thr; group = bid&7 (dir = group>>2, batch octet b0), 32 WGs
// per group each owning 16 h-cols (hs = bid>>3). Thread (kc=t&31, cg=t>>5)
// holds w[c][2jj+jo] = Wh[2kc+jo+64jj][col(cg*6+c)] in VGPRs (96 regs);
// hbuf reads are float2 (ds_read_b64, conflict-free).
// Sync per step (no cache-maintenance ops at all):
//   h publish  : system-scope relaxed atomic store (write-through, sc0|sc1;
//                no dirty local L2 line is ever created for h)
//   vmcnt(0)+syncthreads -> h stores complete AT the coherence point
//   t0: fetch_add(myslot,1) RELAXED  (RMW executes at coherence point)
//   t<32: relaxed RMW-poll of the 32 slots (always fresh; 64B-strided)
//   h consume  : system-scope relaxed atomic load (reads coherence point,
//                never allocates -> stale local copies cannot exist)
// xp / weights stay warm in L2 (no buffer_inv in the loop).
// h-state double-buffered; max inter-WG skew is 1 step, tolerated by the
// ping-pong (a WG posts its slot only after its reads of buf[s&1] are done).
__global__ __launch_bounds__(256, 1)
void gru_scan_kernel(const float* __restrict__ xp_f, const float* __restrict__ xp_b,
                     const float* __restrict__ fWh, const float* __restrict__ bWh,
                     const float* __restrict__ fbhn, const float* __restrict__ bbhn,
                     float* __restrict__ hstate, float* __restrict__ hcat,
                     unsigned* __restrict__ flags)
{
  const int bid   = blockIdx.x;
  const int group = bid & 7;
  const int hs    = bid >> 3;          // 0..31: h-col slice AND wg-index in group
  const int dir   = group >> 2;
  const int b0    = (group & 3) * 8;

  const float* __restrict__ xp  = dir ? xp_b : xp_f;
  const float* __restrict__ Wh  = dir ? bWh  : fWh;
  const float* __restrict__ bhn = dir ? bbhn : fbhn;

  const int t  = threadIdx.x;
  const int kc = t & 31;
  const int cg = t >> 5;

  // LDS: single buffer, time-multiplexed. hbuf[8*512] -> part[384][33];
  // wtmp[512][17] overlays during one-time weight load. 51,200 B total.
  __shared__ float smem[384 * 33];
  __shared__ float nlin[128];
  float* hbuf        = smem;
  float (*part)[33]  = reinterpret_cast<float(*)[33]>(smem);
  float (*wtmp)[17]  = reinterpret_cast<float(*)[17]>(smem);

  // --- one-time coalesced weight load (LDS-mediated, gate by gate) ---
  float w[6][16];
  for (int q = 0; q < 3; ++q) {
    #pragma unroll
    for (int v = 0; v < 8; ++v) {
      const int f   = v * 256 + t;                 // 0..2047
      const int row = f >> 2, c4 = f & 3;
      const float4 val = *reinterpret_cast<const float4*>(
          &Wh[(size_t)row * 1536 + q * 512 + hs * 16 + c4 * 4]);
      wtmp[row][c4 * 4 + 0] = val.x;
      wtmp[row][c4 * 4 + 1] = val.y;
      wtmp[row][c4 * 4 + 2] = val.z;
      wtmp[row][c4 * 4 + 3] = val.w;
    }
    __syncthreads();
    #pragma unroll
    for (int c = 0; c < 6; ++c) {
      const int cl = cg * 6 + c;
      if ((cl >> 4) == q) {
        #pragma unroll
        for (int jj = 0; jj < 8; ++jj)
          #pragma unroll
          for (int jo = 0; jo < 2; ++jo)
            w[c][jj * 2 + jo] = wtmp[kc * 2 + jo + 64 * jj][cl & 15];
      }
    }
    __syncthreads();
  }

  // roles: low 128 threads -> r,z + combine + output; next 128 -> n-linear.
  const bool lowR  = (t < 128);
  const int  rt    = lowR ? t : (t - 128);
  const int  gi    = rt & 15;
  const int  gb    = rt >> 4;
  const float bhn_v = (!lowR) ? bhn[hs * 16 + gi] : 0.f;

  unsigned* myslot = flags + (group * 32 + hs) * 16;   // 64B-strided slots

  for (int s = 0; s < 512; ++s) {
    const int ts = dir ? (511 - s) : s;
    const float* __restrict__ hread  = hstate + (size_t)(s & 1) * 32768;
    float* __restrict__       hwrite = hstate + (size_t)((s + 1) & 1) * 32768;

    // --- stage h (system-scope bypass loads: always fresh, never cached) ---
    float tmp[16];
    #pragma unroll
    for (int v = 0; v < 16; ++v) {
      const int idx = v * 256 + t;
      const int b = idx >> 9, k = idx & 511;
      tmp[v] = HLOAD(&hread[((size_t)(dir * 32 + b0 + b) << 9) + k]);
    }
    float xr = 0.f, xz = 0.f, xn = 0.f, hold = 0.f;
    if (lowR) {
      const float* xrow = xp + ((size_t)(b0 + gb) * 512 + ts) * 1536 + hs * 16 + gi;
      xr = xrow[0]; xz = xrow[512]; xn = xrow[1024];
    }
    #pragma unroll
    for (int v = 0; v < 16; ++v) hbuf[v * 256 + t] = tmp[v];
    __syncthreads();
    if (lowR) hold = hbuf[gb * 512 + hs * 16 + gi];

    // --- partial dots: acc[c][b] = sum_k w[c][k] * h[b][2kc+jo+64jj] ---
    float acc[6][8];
    #pragma unroll
    for (int c = 0; c < 6; ++c)
      #pragma unroll
      for (int b = 0; b < 8; ++b) acc[c][b] = 0.f;
    #pragma unroll
    for (int b = 0; b < 8; ++b) {
      #pragma unroll
      for (int jj = 0; jj < 8; ++jj) {
        const float2 h2 = *reinterpret_cast<const float2*>(
            &hbuf[b * 512 + kc * 2 + 64 * jj]);        // ds_read_b64, conflict-free
        #pragma unroll
        for (int c = 0; c < 6; ++c)
          acc[c][b] = fmaf(w[c][jj * 2], h2.x,
                      fmaf(w[c][jj * 2 + 1], h2.y, acc[c][b]));
      }
    }
    __syncthreads();              // hbuf reads complete; smem becomes 'part'
    #pragma unroll
    for (int c = 0; c < 6; ++c)
      #pragma unroll
      for (int b = 0; b < 8; ++b)
        part[b * 48 + cg * 6 + c][kc] = acc[c][b];     // batch-major: 2-way max
    __syncthreads();

    // --- split reduction (2-way banks: dr mod 32 distinct across lanes) ---
    float r_ = 0.f, z_ = 0.f;
    if (lowR) {
      float gr = 0.f, gz = 0.f;
      const int dr = gb * 48 + gi;
      const int dz = gb * 48 + 16 + gi;
      #pragma unroll
      for (int k = 0; k < 32; ++k) gr += part[dr][k];
      #pragma unroll
      for (int k = 0; k < 32; ++k) gz += part[dz][k];
      r_ = 1.f / (1.f + expf(-(xr + gr)));
      z_ = 1.f / (1.f + expf(-(xz + gz)));
    } else {
      float gn = 0.f;
      const int dn = gb * 48 + 32 + gi;
      #pragma unroll
      for (int k = 0; k < 32; ++k) gn += part[dn][k];
      nlin[rt] = gn + bhn_v;
    }
    __syncthreads();
    if (lowR) {
      const float n_   = tanhf(xn + r_ * nlin[rt]);
      const float hnew = (1.f - z_) * n_ + z_ * hold;
      HSTORE(&hwrite[((size_t)(dir * 32 + b0 + gb) << 9) + hs * 16 + gi], hnew);
      hcat[((size_t)(b0 + gb) * 512 + ts) * 1024 + (size_t)dir * 512 + hs * 16 + gi] = hnew;
    }

    // --- slot barrier: pure relaxed RMWs, no cache-maintenance ops ---
    const unsigned target = (unsigned)(s + 1);
    asm volatile("s_waitcnt vmcnt(0)" ::: "memory");   // h at coherence point
    __syncthreads();                                   // all waves done
    if (t == 0)
      __hip_atomic_fetch_add(myslot, 1u, __ATOMIC_RELAXED, __HIP_MEMORY_SCOPE_AGENT);
    if (t < 32) {
      unsigned* ps = flags + (group * 32 + t) * 16;
      while (__hip_atomic_fetch_add(ps, 0u, __ATOMIC_RELAXED, __HIP_MEMORY_SCOPE_AGENT) < target)
        __builtin_amdgcn_s_sleep(1);
    }
    __syncthreads();                                   // polls satisfied -> go
  }
}

// ---------------- Q = L L^T from vflat (Dg[32] | tril[496]) ----------------
__global__ __launch_bounds__(256)
void q_kernel(const float* __restrict__ vflat, float* __restrict__ qout)
{
  __shared__ float vrow[528];
  __shared__ float Ls[32][33];
  const int bt = blockIdx.x;
  const int t  = threadIdx.x;
  const float* src = vflat + (size_t)bt * 528;

  for (int i = t; i < 528; i += 256) vrow[i] = src[i];
  for (int i = t; i < 32 * 33; i += 256) (&Ls[0][0])[i] = 0.f;
  __syncthreads();
  for (int e = t; e < 496; e += 256) {
    int r = (int)((1.f + sqrtf(1.f + 8.f * (float)e)) * 0.5f);
    while (r * (r - 1) / 2 > e) --r;
    while ((r + 1) * r / 2 <= e) ++r;
    const int c = e - r * (r - 1) / 2;
    Ls[r][c] = vrow[32 + e];
  }
  if (t < 32) Ls[t][t] = expf(vrow[t]) + EPS_Q;
  __syncthreads();

  float* dst = qout + (size_t)bt * 1024;
  #pragma unroll
  for (int p = 0; p < 4; ++p) {
    const int o = t + p * 256;
    const int i = o >> 5, j = o & 31;
    const int kmax = (i < j) ? i : j;
    float sum = 0.f;
    for (int k = 0; k <= kmax; ++k) sum += Ls[i][k] * Ls[j][k];
    dst[o] = sum;
  }
}

// ---------------- launch ----------------
extern "C" void kernel_launch(void* const* d_in, const int* in_sizes, int n_in,
                              void* d_out, int out_size, void* d_ws, size_t ws_size,
                              hipStream_t stream)
{
  const float* x    = (const float*)d_in[0];
  const float* iW1  = (const float*)d_in[1];
  const float* ib1  = (const float*)d_in[2];
  const float* iW2  = (const float*)d_in[3];
  const float* ib2  = (const float*)d_in[4];
  const float* fWi  = (const float*)d_in[5];
  const float* fbi  = (const float*)d_in[6];
  const float* fWh  = (const float*)d_in[7];
  const float* fbhn = (const float*)d_in[8];
  const float* bWi  = (const float*)d_in[9];
  const float* bbi  = (const float*)d_in[10];
  const float* bWh  = (const float*)d_in[11];
  const float* bbhn = (const float*)d_in[12];
  const float* mW1  = (const float*)d_in[13];
  const float* mb1  = (const float*)d_in[14];
  const float* mW2  = (const float*)d_in[15];
  const float* mb2  = (const float*)d_in[16];
  const float* vW1  = (const float*)d_in[17];
  const float* vb1  = (const float*)d_in[18];
  const float* vW2  = (const float*)d_in[19];
  const float* vb2  = (const float*)d_in[20];
  const float* dW1  = (const float*)d_in[21];
  const float* db1  = (const float*)d_in[22];
  const float* dW2  = (const float*)d_in[23];
  const float* db2  = (const float*)d_in[24];
  (void)in_sizes; (void)n_in; (void)out_size;

  float* Aout = (float*)d_out;                 // floats: A 16,777,216
  float* bout = Aout + 16777216;               //          b    524,288
  float* Qout = Aout + 17301504;               //          Q 16,777,216

  const int M = 16384;                         // B*T
  float* ws = (float*)d_ws;

  const size_t needB = 54592256ull * 4ull;     // 218.4 MB (proven available r3/r5)
  if (ws_size < needB) return;                 // clean validation failure

  float* hid    = ws;                          //  4,194,304
  float* u      = ws + 4194304;                //  8,388,608
  float* xpf    = ws + 12582912;               // 25,165,824
  float* hcat   = ws + 37748736;               // 16,777,216
  float* hstate = ws + 54525952;               //     65,536
  float* xpb    = Aout;                        // d_out[0..25.17M): dead before
  float* vflat  = Aout;                        //   b/Q/A writes
  unsigned* flags = (unsigned*)(Aout + 25165824);  // past xpb; dead after scan

  init_ws_kernel<<<dim3(256), dim3(256), 0, stream>>>(hstate, flags);
  // input MLP
  gemm_bias_kernel<true ><<<dim3(2, 128),  dim3(256), 0, stream>>>(x,   iW1, ib1, hid, M, 256,  128);
  gemm_bias_kernel<false><<<dim3(4, 128),  dim3(256), 0, stream>>>(hid, iW2, ib2, u,   M, 512,  256);
  // xp = u@Wi + bi (both directions)
  gemm_bias_kernel<false><<<dim3(12, 128), dim3(256), 0, stream>>>(u, fWi, fbi, xpf, M, 1536, 512);
  gemm_bias_kernel<false><<<dim3(12, 128), dim3(256), 0, stream>>>(u, bWi, bbi, xpb, M, 1536, 512);
  // bidirectional GRU scan
  gru_scan_kernel<<<dim3(256), dim3(256), 0, stream>>>(
      xpf, xpb, fWh, bWh, fbhn, bbhn, hstate, hcat, flags);
  // b head
  gemm_bias_kernel<true ><<<dim3(2, 128),  dim3(256), 0, stream>>>(hcat, mW1, mb1, hid,  M, 256,  1024);
  gemm_bias_kernel<false><<<dim3(1, 128),  dim3(256), 0, stream>>>(hid,  mW2, mb2, bout, M, 32,   256);
  // v head -> vflat -> Q
  gemm_bias_kernel<true ><<<dim3(2, 128),  dim3(256), 0, stream>>>(hcat, vW1, vb1, hid,   M, 256, 1024);
  gemm_bias_kernel<false><<<dim3(5, 128),  dim3(256), 0, stream>>>(hid,  vW2, vb2, vflat, M, 528, 256);
  q_kernel<<<dim3(16384), dim3(256), 0, stream>>>(vflat, Qout);
  // A head
  gemm_bias_kernel<true ><<<dim3(2, 128),  dim3(256), 0, stream>>>(hcat, dW1, db1, hid,  M, 256,  1024);
  gemm_bias_kernel<false><<<dim3(8, 128),  dim3(256), 0, stream>>>(hid,  dW2, db2, Aout, M, 1024, 256);
}